// Round 5
// baseline (465.357 us; speedup 1.0000x reference)
//
#include <hip/hip_runtime.h>

// Problem constants: B=4, L=4096, C=1024, H=16, W=512, D=64, STRIDE=256
// Only windows 0..7 reach the output; q/k/v needed only for rows [0,2304) per batch.
#define LQ 2304

typedef __attribute__((ext_vector_type(8))) short bf16x8;
typedef __attribute__((ext_vector_type(8))) unsigned short u16x8;
typedef __attribute__((ext_vector_type(4))) float f32x4;
typedef __attribute__((ext_vector_type(4))) unsigned int u32x4;

#define MFMA(a, b, c) __builtin_amdgcn_mfma_f32_16x16x32_bf16((a), (b), (c), 0, 0, 0)
#define AS1 __attribute__((address_space(1)))
#define AS3 __attribute__((address_space(3)))

static __device__ __forceinline__ unsigned short f2bf(float f) {
  unsigned int u = __builtin_bit_cast(unsigned int, f);
  u += 0x7fffu + ((u >> 16) & 1u);
  return (unsigned short)(u >> 16);
}

// pack two positive f32 into bf16x2 by byte-perm truncation (caller pre-biases)
static __device__ __forceinline__ unsigned int pkbf(float hi, float lo) {
  return __builtin_amdgcn_perm(__builtin_bit_cast(unsigned int, hi),
                               __builtin_bit_cast(unsigned int, lo), 0x07060302u);
}

// async 16B/lane global->LDS; LDS image is wave-uniform base + lane*16 (no padding!)
static __device__ __forceinline__ void lds16(const unsigned short* g, unsigned short* l) {
  __builtin_amdgcn_global_load_lds((AS1 const unsigned int*)g, (AS3 unsigned int*)l, 16, 0, 0);
}

// ---------------- fused preprocessing: x fp32->bf16 + both weight transposes
static __device__ __forceinline__ void transpose_body(const float* __restrict__ src,
                                                      unsigned short* __restrict__ dst,
                                                      int K, int N, int bx, int by, int tid,
                                                      float (*t)[33]) {
  int bn = bx * 32, bk = by * 32;
  int tx = tid & 31, ty = tid >> 5;
  for (int i = ty; i < 32; i += 8)
    t[i][tx] = src[(size_t)(bk + i) * N + bn + tx];
  __syncthreads();
  for (int i = ty; i < 32; i += 8)
    dst[(size_t)(bn + i) * K + bk + tx] = f2bf(t[tx][i]);
}

__global__ __launch_bounds__(256) void preprocess(const float* __restrict__ x,
                                                  unsigned short* __restrict__ xbf,
                                                  const float* __restrict__ wqkv,
                                                  unsigned short* __restrict__ wqkvT,
                                                  const float* __restrict__ wout,
                                                  unsigned short* __restrict__ woutT) {
  __shared__ float t[32][33];
  int bid = blockIdx.x, tid = threadIdx.x;
  if (bid < 4608) {
    int idx = bid * 256 + tid;
    int b = idx / 294912;               // 294912 = 2304*128
    int g = idx - b * 294912;
    int row = g >> 7, c8 = (g & 127) * 8;
    const float* src = x + ((size_t)b * 4096 + row) * 1024 + c8;
    float4 f0 = *(const float4*)src;
    float4 f1 = *(const float4*)(src + 4);
    u16x8 u;
    u[0] = f2bf(f0.x); u[1] = f2bf(f0.y); u[2] = f2bf(f0.z); u[3] = f2bf(f0.w);
    u[4] = f2bf(f1.x); u[5] = f2bf(f1.y); u[6] = f2bf(f1.z); u[7] = f2bf(f1.w);
    *(u16x8*)(xbf + ((size_t)b * 2304 + row) * 1024 + c8) = u;
  } else if (bid < 7680) {
    int tb = bid - 4608;
    transpose_body(wqkv, wqkvT, 1024, 3072, tb % 96, tb / 96, tid, t);
  } else {
    int tb = bid - 7680;
    transpose_body(wout, woutT, 1024, 1024, tb & 31, tb >> 5, tid, t);
  }
}

// ---------------- QKV projection GEMM: tile 128x128, BK=64, global_load_lds staging
// with 16B-chunk XOR swizzle. Epilogue writes q (B,H,2304,64; pre-scaled), k with a
// per-key chunk swizzle, and v TRANSPOSED (B,H,64,2304) with the PV-perm and a
// per-d chunk swizzle baked in, so attention can stage K/V as flat DMA copies.
#define K2SCALE 0.18033688011112042f
__global__ __launch_bounds__(256) void qkv_gemm(const unsigned short* __restrict__ xbf,
                                                const float* __restrict__ bqkv,
                                                const unsigned short* __restrict__ wT,
                                                unsigned short* __restrict__ qws,
                                                unsigned short* __restrict__ kws,
                                                unsigned short* __restrict__ vws) {
  __shared__ __align__(16) unsigned short As[128 * 64];
  __shared__ __align__(16) unsigned short Bs[128 * 64];
  const int tid = threadIdx.x;
  const int mt = blockIdx.y;
  const int nt = blockIdx.x;
  const int bidx = mt / 18;
  const int l0 = (mt % 18) * 128;
  const int n0 = nt * 128;
  const int lane = tid & 63, wv = tid >> 6;
  const int wm = (wv >> 1) * 64, wn = (wv & 1) * 64;
  const int l16 = lane & 15, quad = lane >> 4;

  const int srow = lane >> 3;
  const int sc = ((lane & 7) ^ srow) * 8;
  const unsigned short* ga = xbf + ((size_t)(bidx * LQ + l0 + wv * 32 + srow)) * 1024 + sc;
  const unsigned short* gb = wT + ((size_t)(n0 + wv * 32 + srow)) * 1024 + sc;
  unsigned short* la = As + wv * 2048;
  unsigned short* lb = Bs + wv * 2048;
  const int xsw = (l16 & 7) * 8;

  const f32x4 zero4 = {0.f, 0.f, 0.f, 0.f};
  f32x4 acc[4][4];
#pragma unroll
  for (int i = 0; i < 4; i++)
#pragma unroll
    for (int j = 0; j < 4; j++) acc[i][j] = zero4;

  for (int k0 = 0; k0 < 1024; k0 += 64) {
    __syncthreads();
#pragma unroll
    for (int j = 0; j < 4; j++) {
      lds16(ga + j * 8 * 1024, la + j * 512);
      lds16(gb + j * 8 * 1024, lb + j * 512);
    }
    __syncthreads();
#pragma unroll
    for (int kh = 0; kh < 2; kh++) {
      bf16x8 af[4], bfv[4];
#pragma unroll
      for (int i = 0; i < 4; i++)
        af[i] = *(const bf16x8*)(&As[(wm + i * 16 + l16) * 64 + (((kh << 5) + quad * 8) ^ xsw)]);
#pragma unroll
      for (int j = 0; j < 4; j++)
        bfv[j] = *(const bf16x8*)(&Bs[(wn + j * 16 + l16) * 64 + (((kh << 5) + quad * 8) ^ xsw)]);
#pragma unroll
      for (int i = 0; i < 4; i++)
#pragma unroll
        for (int j = 0; j < 4; j++)
          acc[i][j] = MFMA(af[i], bfv[j], acc[i][j]);
    }
    ga += 64;
    gb += 64;
  }

#pragma unroll
  for (int j = 0; j < 4; j++) {
    int col = n0 + wn + j * 16 + l16;   // [0,3072)
    int which = col >> 10;
    int hcol = (col >> 6) & 15;
    int dcol = col & 63;
    float bias = bqkv[col];
    size_t bh = (size_t)bidx * 16 + hcol;
    if (which == 0) {
      size_t cbase = bh * 2304 * 64 + dcol;
#pragma unroll
      for (int i = 0; i < 4; i++) {
        int key0 = l0 + wm + i * 16 + quad * 4;
#pragma unroll
        for (int r = 0; r < 4; r++)
          qws[cbase + (size_t)(key0 + r) * 64] = f2bf((acc[i][j][r] + bias) * K2SCALE);
      }
    } else if (which == 1) {
#pragma unroll
      for (int i = 0; i < 4; i++) {
        int key0 = l0 + wm + i * 16 + quad * 4;
#pragma unroll
        for (int r = 0; r < 4; r++) {
          int key = key0 + r;
          size_t addr = (bh * 2304 + key) * 64 + (((dcol >> 3) ^ (key & 7)) << 3) + (dcol & 7);
          kws[addr] = f2bf(acc[i][j][r] + bias);
        }
      }
    } else {
      size_t rowb = (bh * 64 + dcol) * 2304;
#pragma unroll
      for (int i = 0; i < 4; i++) {
        int key0 = l0 + wm + i * 16 + quad * 4;   // multiple of 4
        // PV perm: key = 32c + 16t + 4q' + r -> pos = 32c + 8q' + 4t + r
        int pos = ((key0 >> 5) & 3) * 32 + ((key0 >> 2) & 3) * 8 + ((key0 >> 4) & 1) * 4;
        int kk = (key0 & ~127) + (((pos >> 3) ^ (dcol & 7)) << 3) + (pos & 7);
        ushort4 u;
        u.x = f2bf(acc[i][j][0] + bias);
        u.y = f2bf(acc[i][j][1] + bias);
        u.z = f2bf(acc[i][j][2] + bias);
        u.w = f2bf(acc[i][j][3] + bias);
        *(ushort4*)(vws + rowb + kk) = u;
      }
    }
  }
}

// ---------------- attention: one block per (window n, head h, batch b), 1024 threads
// (16 waves x 32 q). Double-buffered 256-key tiles: K (256x64) and V^T (64x256) staged
// entirely by global_load_lds flat copies (perm+swizzle pre-baked in kws/vws layouts);
// one barrier per tile, prefetch overlaps compute. Computes O^T = V^T P^T (operand
// swap; A/B fragment layouts are identical), so each lane holds 4 consecutive output
// channels -> 8B stores into 128B-row o layout [H][16384][64] (chunk-swizzled for
// out_gemm's flat staging). Bounded scores -> no max subtraction; q pre-scaled.
#define ATTN_LDS 131072

__global__ __launch_bounds__(1024, 4) void attn_kernel(const unsigned short* __restrict__ q,
                                                       const unsigned short* __restrict__ k,
                                                       const unsigned short* __restrict__ v,
                                                       unsigned short* __restrict__ o) {
  extern __shared__ unsigned short lds[];
  // ushort offsets: [0) K0 [16384) K1 [32768) V0 [49152) V1
  const int bid = blockIdx.x;
  const int n = bid >> 6, bh = bid & 63;      // id%8 = h&7 -> same (b,h) on same XCD
  const int b = bh >> 4, h = bh & 15;
  const unsigned short* qg = q + ((size_t)bh * 2304 + n * 256) * 64;
  const unsigned short* kg = k + ((size_t)bh * 2304 + n * 256) * 64;
  const unsigned short* vgb = v + (size_t)bh * 64 * 2304 + n * 256;
  const int tid = threadIdx.x;
  const int lane = tid & 63, wv = tid >> 6;   // wv 0..15
  const int l16 = lane & 15, quad = lane >> 4;
  const int xs = l16 & 7;
  const f32x4 zero4 = {0.f, 0.f, 0.f, 0.f};
  const float RB = 0.002815015607053277f;     // log2(1 + 2^-9)

  // stage tile kt into buffer buf (flat DMA copies; 4 lds16 per thread)
  auto stage = [&](int kt, int buf) {
    const unsigned short* kgt = kg + kt * 256 * 64;
    unsigned short* kb = lds + buf * 16384;
    lds16(kgt + (wv * 64 + lane) * 8, kb + wv * 512);
    lds16(kgt + (1024 + wv * 64 + lane) * 8, kb + 8192 + wv * 512);
    unsigned short* vb = lds + 32768 + buf * 16384;
    const unsigned short* vgt = vgb + kt * 256;
    int d0 = wv * 2;
    lds16(vgt + (size_t)(d0 + (lane >> 5)) * 2304 + (lane & 31) * 8, vb + d0 * 256);
    int d1 = 32 + wv * 2;
    lds16(vgt + (size_t)(d1 + (lane >> 5)) * 2304 + (lane & 31) * 8, vb + d1 * 256);
  };

  bf16x8 qf0[2], qf1[2];
#pragma unroll
  for (int qs = 0; qs < 2; qs++) {
    int qrow = wv * 32 + qs * 16 + l16;
    qf0[qs] = *(const bf16x8*)(qg + (size_t)qrow * 64 + quad * 8);
    qf1[qs] = *(const bf16x8*)(qg + (size_t)qrow * 64 + quad * 8 + 32);
  }
  f32x4 O[2][4];
#pragma unroll
  for (int qs = 0; qs < 2; qs++)
#pragma unroll
    for (int dt = 0; dt < 4; dt++) O[qs][dt] = zero4;
  float lsum[2] = {0.f, 0.f};

  stage(0, 0);
  for (int kt = 0; kt < 2; kt++) {
    __syncthreads();                 // drains tile-kt DMA; syncs buffer reuse
    if (kt == 0) stage(1, 1);        // prefetch overlaps tile-0 compute
    const unsigned short* KB = lds + kt * 16384;
    const unsigned short* VB = lds + 32768 + kt * 16384;
    const int ca = (quad ^ xs) << 3, cb = ((4 + quad) ^ xs) << 3;
#pragma unroll
    for (int c = 0; c < 8; c++) {
      const unsigned short* krow0 = KB + (c * 32 + l16) * 64;
      const unsigned short* krow1 = krow0 + 16 * 64;
      bf16x8 ka0 = *(const bf16x8*)(krow0 + ca);
      bf16x8 ka1 = *(const bf16x8*)(krow0 + cb);
      bf16x8 kb0 = *(const bf16x8*)(krow1 + ca);
      bf16x8 kb1 = *(const bf16x8*)(krow1 + cb);
      int vco = (c >> 2) * 128 + ((((c & 3) * 4 + quad) ^ xs) << 3);
      bf16x8 vf[4];
#pragma unroll
      for (int dt = 0; dt < 4; dt++)
        vf[dt] = *(const bf16x8*)(VB + (dt * 16 + l16) * 256 + vco);
#pragma unroll
      for (int qs = 0; qs < 2; qs++) {
        f32x4 s0 = zero4, s1 = zero4;
        s0 = MFMA(ka0, qf0[qs], s0);
        s0 = MFMA(ka1, qf1[qs], s0);
        s1 = MFMA(kb0, qf0[qs], s1);
        s1 = MFMA(kb1, qf1[qs], s1);
        float p0[4], p1[4], ls = 0.f;
#pragma unroll
        for (int r = 0; r < 4; r++) {
          p0[r] = __builtin_amdgcn_exp2f(s0[r] + RB);
          p1[r] = __builtin_amdgcn_exp2f(s1[r] + RB);
          ls += p0[r] + p1[r];
        }
        lsum[qs] += ls;
        u32x4 pw;
        pw[0] = pkbf(p0[1], p0[0]);
        pw[1] = pkbf(p0[3], p0[2]);
        pw[2] = pkbf(p1[1], p1[0]);
        pw[3] = pkbf(p1[3], p1[2]);
        bf16x8 pf = __builtin_bit_cast(bf16x8, pw);
#pragma unroll
        for (int dt = 0; dt < 4; dt++)
          O[qs][dt] = MFMA(vf[dt], pf, O[qs][dt]);   // O^T = V^T P^T
      }
    }
  }

#pragma unroll
  for (int qs = 0; qs < 2; qs++) {
    float ls = lsum[qs];
    ls += __shfl_xor(ls, 16);
    ls += __shfl_xor(ls, 32);
    float linv = 1.0f / ls;          // valid for q = l16 (all regs of this lane)
    size_t gr = (size_t)b * 4096 + n * 512 + wv * 32 + qs * 16 + l16;
    unsigned short* ob = o + ((size_t)h * 16384 + gr) * 64 + (quad & 1) * 4;
#pragma unroll
    for (int dt = 0; dt < 4; dt++) {
      int ch = (((2 * dt + (quad >> 1)) ^ xs) << 3);
      ushort4 u;
      u.x = f2bf(O[qs][dt][0] * linv);
      u.y = f2bf(O[qs][dt][1] * linv);
      u.z = f2bf(O[qs][dt][2] * linv);
      u.w = f2bf(O[qs][dt][3] * linv);
      *(ushort4*)(ob + ch) = u;
    }
  }
}

// ---------------- output projection GEMM: A = o [H][16384][64] (chunk-swizzled,
// flat-copy staging), B = w_out^T (srow/sc swizzled staging). BK=64 = one head.
__global__ __launch_bounds__(256) void out_gemm(const unsigned short* __restrict__ A,
                                                const unsigned short* __restrict__ wT,
                                                const float* __restrict__ bout,
                                                float* __restrict__ out) {
  __shared__ __align__(16) unsigned short As[128 * 64];
  __shared__ __align__(16) unsigned short Bs[128 * 64];
  const int tid = threadIdx.x;
  const int m0 = blockIdx.y * 128;
  const int n0 = blockIdx.x * 128;
  const int lane = tid & 63, wv = tid >> 6;
  const int wm = (wv >> 1) * 64, wn = (wv & 1) * 64;
  const int l16 = lane & 15, quad = lane >> 4;

  const unsigned short* ga = A + (size_t)m0 * 64;   // advances by 16384*64 per head
  const int srow = lane >> 3;
  const int sc = ((lane & 7) ^ srow) * 8;
  const unsigned short* gb = wT + ((size_t)(n0 + wv * 32 + srow)) * 1024 + sc;
  unsigned short* lb = Bs + wv * 2048;
  const int xsw = (l16 & 7) * 8;

  const f32x4 zero4 = {0.f, 0.f, 0.f, 0.f};
  f32x4 acc[4][4];
#pragma unroll
  for (int i = 0; i < 4; i++)
#pragma unroll
    for (int j = 0; j < 4; j++) acc[i][j] = zero4;

  for (int kk = 0; kk < 16; kk++) {
    __syncthreads();
#pragma unroll
    for (int j = 0; j < 4; j++) {
      lds16(ga + (j * 256 + wv * 64 + lane) * 8, As + (j * 256 + wv * 64) * 8);
      lds16(gb + j * 8 * 1024, lb + j * 512);
    }
    __syncthreads();
#pragma unroll
    for (int kh = 0; kh < 2; kh++) {
      bf16x8 af[4], bfv[4];
#pragma unroll
      for (int i = 0; i < 4; i++)
        af[i] = *(const bf16x8*)(&As[(wm + i * 16 + l16) * 64 + (((kh << 5) + quad * 8) ^ xsw)]);
#pragma unroll
      for (int j = 0; j < 4; j++)
        bfv[j] = *(const bf16x8*)(&Bs[(wn + j * 16 + l16) * 64 + (((kh << 5) + quad * 8) ^ xsw)]);
#pragma unroll
      for (int i = 0; i < 4; i++)
#pragma unroll
        for (int j = 0; j < 4; j++)
          acc[i][j] = MFMA(af[i], bfv[j], acc[i][j]);
    }
    ga += 16384 * 64;
    gb += 64;
  }

#pragma unroll
  for (int j = 0; j < 4; j++) {
    int col = n0 + wn + j * 16 + l16;
    float bias = bout[col];
#pragma unroll
    for (int i = 0; i < 4; i++) {
      int row = m0 + wm + i * 16 + quad * 4;
#pragma unroll
      for (int r = 0; r < 4; r++)
        out[(size_t)(row + r) * 1024 + col] = acc[i][j][r] + bias;
    }
  }
}

// ---------------- workspace layout (bytes); xbf aliases ows (dead until attn writes)
#define WQKVT_OFF 0u
#define WOUTT_OFF (WQKVT_OFF + 3072u * 1024u * 2u)          // 6291456
#define QWS_OFF   (WOUTT_OFF + 1024u * 1024u * 2u)          // 8388608
#define KVQ_SZ    (4u * 16u * 2304u * 64u * 2u)             // 18874368
#define KWS_OFF   (QWS_OFF + KVQ_SZ)
#define VWS_OFF   (KWS_OFF + KVQ_SZ)
#define OWS_OFF   (VWS_OFF + KVQ_SZ)                        // 65011712
#define XBF_OFF   OWS_OFF                                   // alias: 18.9MB <= 33.5MB

extern "C" void kernel_launch(void* const* d_in, const int* in_sizes, int n_in,
                              void* d_out, int out_size, void* d_ws, size_t ws_size,
                              hipStream_t stream) {
  const float* x     = (const float*)d_in[0];
  const float* w_qkv = (const float*)d_in[1];
  const float* b_qkv = (const float*)d_in[2];
  const float* w_out = (const float*)d_in[3];
  const float* b_out = (const float*)d_in[4];
  float* out = (float*)d_out;
  char* ws = (char*)d_ws;

  unsigned short* wqkvT = (unsigned short*)(ws + WQKVT_OFF);
  unsigned short* woutT = (unsigned short*)(ws + WOUTT_OFF);
  unsigned short* qws   = (unsigned short*)(ws + QWS_OFF);
  unsigned short* kws   = (unsigned short*)(ws + KWS_OFF);
  unsigned short* vws   = (unsigned short*)(ws + VWS_OFF);
  unsigned short* ows   = (unsigned short*)(ws + OWS_OFF);
  unsigned short* xbf   = (unsigned short*)(ws + XBF_OFF);

  preprocess<<<8704, 256, 0, stream>>>(x, xbf, w_qkv, wqkvT, w_out, woutT);

  qkv_gemm<<<dim3(24, 72), 256, 0, stream>>>(xbf, b_qkv, wqkvT, qws, kws, vws);

  (void)hipFuncSetAttribute((const void*)attn_kernel,
                            hipFuncAttributeMaxDynamicSharedMemorySize, ATTN_LDS);
  attn_kernel<<<512, 1024, ATTN_LDS, stream>>>(qws, kws, vws, ows);

  out_gemm<<<dim3(8, 128), 256, 0, stream>>>(ows, woutT, b_out, out);
}